// Round 8
// baseline (973.474 us; speedup 1.0000x reference)
//
#include <hip/hip_runtime.h>
#include <cmath>

#define NN 100000
#define NE 1600000
#define HD 128

typedef __attribute__((ext_vector_type(8))) short bf16x8;
typedef __attribute__((ext_vector_type(4))) float f32x4;

__device__ inline short f2bf(float f) {
  union { float f; unsigned u; } x; x.f = f;
  unsigned r = x.u + 0x7fff + ((x.u >> 16) & 1);
  return (short)(r >> 16);
}
__device__ inline float bf2f(short s) {
  union { float f; unsigned u; } x;
  x.u = ((unsigned)(unsigned short)s) << 16;
  return x.f;
}
__device__ inline void split2(float v, short& hi, short& lo) {
  hi = f2bf(v);
  lo = f2bf(v - bf2f(hi));
}

// ---------------- prep: split f32 x into bf16 hi/lo planes, KP=136 ----------
// cols 133..135 zero; row NN zero-padded is unnecessary (W rows >=133 are 0),
// but we still guard row<n so reads stay in-bounds; planes have +1 pad row.
__global__ void split_x(const float* __restrict__ x,
                        short* __restrict__ Phi, short* __restrict__ Plo, int n) {
  int i = blockIdx.x * blockDim.x + threadIdx.x;
  int total = (n + 1) * 136;
  if (i >= total) return;
  int row = i / 136;
  int col = i - row * 136;
  float v = (row < n && col < 133) ? x[(size_t)row * 133 + col] : 0.f;
  short hi, lo;
  split2(v, hi, lo);
  Phi[i] = hi;
  Plo[i] = lo;
}

// ---------------- MFMA GEMM: C[n][128] = A[n][K] @ W[K][128] ----------------
// A is pre-split bf16 hi/lo planes (row stride KP). W staged in LDS in
// fragment order (hi+lo). 3-term: Ahi*Whi + Ahi*Wlo + Alo*Whi (~2^-17 rel).
// No per-element VALU split in the hot loop; all frags in named registers.
// Output written as split bf16 planes (consumed by agg gather / next layer).
template <int KST>
__global__ __launch_bounds__(256, 2) void gemm_bf(
    const short* __restrict__ Ahi, const short* __restrict__ Alo, int KP,
    const float* __restrict__ W, int K,
    short* __restrict__ Chi, short* __restrict__ Clo, int n) {
  __shared__ short Whi[KST * 8 * 64 * 8];
  __shared__ short Wlo[KST * 8 * 64 * 8];
  int t = threadIdx.x;
  for (int i = t; i < KST * 32 * 128; i += 256) {
    int k = i >> 7, col = i & 127;
    float v = (k < K) ? W[k * 128 + col] : 0.f;
    short hi, lo;
    split2(v, hi, lo);
    int off = (((k >> 5) * 8 + (col >> 4)) * 64 + ((k >> 3) & 3) * 16 + (col & 15)) * 8 + (k & 7);
    Whi[off] = hi;
    Wlo[off] = lo;
  }
  __syncthreads();

  int wave = t >> 6, lane = t & 63;
  int lrow = lane & 15, khalf = lane >> 4;
  int r0 = blockIdx.x * 256 + wave * 64;

  f32x4 acc[4][8];
#pragma unroll
  for (int rf = 0; rf < 4; ++rf)
#pragma unroll
    for (int cf = 0; cf < 8; ++cf) acc[rf][cf] = (f32x4){0.f, 0.f, 0.f, 0.f};

#pragma unroll
  for (int ks = 0; ks < KST; ++ks) {
    bf16x8 ahi[4], alo[4];
#pragma unroll
    for (int rf = 0; rf < 4; ++rf) {
      int row = r0 + rf * 16 + lrow;
      if (row < n) {
        size_t base = (size_t)row * KP + ks * 32 + khalf * 8;
        ahi[rf] = *(const bf16x8*)(Ahi + base);
        alo[rf] = *(const bf16x8*)(Alo + base);
      } else {
        ahi[rf] = (bf16x8){0, 0, 0, 0, 0, 0, 0, 0};
        alo[rf] = (bf16x8){0, 0, 0, 0, 0, 0, 0, 0};
      }
    }
#pragma unroll
    for (int cf = 0; cf < 8; ++cf) {
      int boff = ((ks * 8 + cf) * 64 + lane) * 8;
      bf16x8 bhi = *(bf16x8*)&Whi[boff];
      bf16x8 blo = *(bf16x8*)&Wlo[boff];
#pragma unroll
      for (int rf = 0; rf < 4; ++rf) {
        acc[rf][cf] = __builtin_amdgcn_mfma_f32_16x16x32_bf16(ahi[rf], bhi, acc[rf][cf], 0, 0, 0);
        acc[rf][cf] = __builtin_amdgcn_mfma_f32_16x16x32_bf16(ahi[rf], blo, acc[rf][cf], 0, 0, 0);
        acc[rf][cf] = __builtin_amdgcn_mfma_f32_16x16x32_bf16(alo[rf], bhi, acc[rf][cf], 0, 0, 0);
      }
    }
  }

#pragma unroll
  for (int rf = 0; rf < 4; ++rf)
#pragma unroll
    for (int cf = 0; cf < 8; ++cf) {
      int rowb = r0 + rf * 16 + khalf * 4;
      int col = cf * 16 + lrow;
#pragma unroll
      for (int j = 0; j < 4; ++j) {
        int row = rowb + j;
        if (row < n) {
          short hi, lo;
          split2(acc[rf][cf][j], hi, lo);
          Chi[(size_t)row * 128 + col] = hi;
          Clo[(size_t)row * 128 + col] = lo;
        }
      }
    }
}

// ---------------- degree count (int atomics) ----------------
__global__ void cnt_kernel(const int* __restrict__ ei, int* __restrict__ cnt, int e) {
  int i = blockIdx.x * blockDim.x + threadIdx.x;
  if (i < e) atomicAdd(&cnt[ei[(size_t)e + i]], 1);
}

__global__ void dinv_kernel(const int* __restrict__ cnt, float* __restrict__ dinv, int n) {
  int i = blockIdx.x * blockDim.x + threadIdx.x;
  if (i < n) dinv[i] = 1.0f / sqrtf((float)cnt[i] + 1.0f);
}

// ---------------- exclusive scan (3 kernels, 1024 elems/block) ----------------
__global__ __launch_bounds__(256) void scan1(const int* __restrict__ cnt, int* __restrict__ excl,
                                             int* __restrict__ partials, int n) {
  __shared__ int sd[256];
  int t = threadIdx.x;
  int base = blockIdx.x * 1024 + t * 4;
  int v[4]; int s = 0;
#pragma unroll
  for (int i = 0; i < 4; ++i) { int idx = base + i; v[i] = (idx < n) ? cnt[idx] : 0; s += v[i]; }
  sd[t] = s;
  __syncthreads();
  for (int off = 1; off < 256; off <<= 1) {
    int x = (t >= off) ? sd[t - off] : 0;
    __syncthreads();
    if (t >= off) sd[t] += x;
    __syncthreads();
  }
  if (t == 255) partials[blockIdx.x] = sd[255];
  int run = sd[t] - s;
#pragma unroll
  for (int i = 0; i < 4; ++i) { int idx = base + i; if (idx < n) excl[idx] = run; run += v[i]; }
}

__global__ __launch_bounds__(256) void scan2(int* __restrict__ partials, int np) {
  __shared__ int sd[256];
  int t = threadIdx.x;
  int v = (t < np) ? partials[t] : 0;
  sd[t] = v;
  __syncthreads();
  for (int off = 1; off < 256; off <<= 1) {
    int x = (t >= off) ? sd[t - off] : 0;
    __syncthreads();
    if (t >= off) sd[t] += x;
    __syncthreads();
  }
  if (t < np) partials[t] = sd[t] - v;
}

__global__ void scan3(int* __restrict__ rowptr, const int* __restrict__ partials, int n, int etot) {
  int i = blockIdx.x * blockDim.x + threadIdx.x;
  if (i < n) rowptr[i] += partials[i >> 10];
  if (i == 0) rowptr[n] = etot;
}

// ---------------- CSR fill: packed (src, coef) ----------------
__global__ void fill_kernel(const int* __restrict__ ei, const float* __restrict__ dinv,
                            const int* __restrict__ rowptr, int* __restrict__ cursor,
                            int2* __restrict__ epack, int e) {
  int i = blockIdx.x * blockDim.x + threadIdx.x;
  if (i >= e) return;
  int s = ei[i];
  int d = ei[(size_t)e + i];
  int p = atomicAdd(&cursor[d], 1);
  epack[rowptr[d] + p] = make_int2(s, __float_as_int(dinv[s] * dinv[d]));
}

// ---------------- aggregation over bf16 hi/lo planes -------------------------
// Gathers h rows from split planes (hi+lo == f32 to 2^-17), reg-cached edge
// batches + readlane broadcast + 4 independent accumulators (round-7 WIN).
// FINAL=false: write tanh result as split planes. FINAL=true: write f32 out.
__device__ inline float2 recon(unsigned uh, unsigned ul) {
  float2 v;
  v.x = __uint_as_float(uh << 16) + __uint_as_float(ul << 16);
  v.y = __uint_as_float(uh & 0xffff0000u) + __uint_as_float(ul & 0xffff0000u);
  return v;
}

template <bool FINAL>
__global__ __launch_bounds__(256) void agg_kernel(
    const short* __restrict__ Phi, const short* __restrict__ Plo,
    const float* __restrict__ dinv,
    const int* __restrict__ rowptr, const int2* __restrict__ epack,
    const float* __restrict__ bias,
    short* __restrict__ Ohi, short* __restrict__ Olo,
    float* __restrict__ outf, int n) {
  int wid = (int)((blockIdx.x * (size_t)blockDim.x + threadIdx.x) >> 6);
  int lane = threadIdx.x & 63;
  if (wid >= n) return;
  float di = dinv[wid];
  const short* phl = Phi + lane * 2;
  const short* pll = Plo + lane * 2;
  float2 hs = recon(*(const unsigned*)(phl + (size_t)wid * HD),
                    *(const unsigned*)(pll + (size_t)wid * HD));
  float2 a0, a1, a2, a3;
  a0.x = hs.x * di * di; a0.y = hs.y * di * di;
  a1.x = a1.y = a2.x = a2.y = a3.x = a3.y = 0.f;
  int beg = rowptr[wid], end = rowptr[wid + 1];
  while (beg < end) {
    int nj = end - beg;
    if (nj > 64) nj = 64;
    int2 ep = (lane < nj) ? epack[beg + lane] : make_int2(0, 0);
    int sreg = ep.x, creg = ep.y;
    int j = 0;
    for (; j + 4 <= nj; j += 4) {
      int s0 = __builtin_amdgcn_readlane(sreg, j + 0);
      int s1 = __builtin_amdgcn_readlane(sreg, j + 1);
      int s2 = __builtin_amdgcn_readlane(sreg, j + 2);
      int s3 = __builtin_amdgcn_readlane(sreg, j + 3);
      float c0 = __int_as_float(__builtin_amdgcn_readlane(creg, j + 0));
      float c1 = __int_as_float(__builtin_amdgcn_readlane(creg, j + 1));
      float c2 = __int_as_float(__builtin_amdgcn_readlane(creg, j + 2));
      float c3 = __int_as_float(__builtin_amdgcn_readlane(creg, j + 3));
      unsigned h0 = *(const unsigned*)(phl + (size_t)s0 * HD);
      unsigned l0 = *(const unsigned*)(pll + (size_t)s0 * HD);
      unsigned h1 = *(const unsigned*)(phl + (size_t)s1 * HD);
      unsigned l1 = *(const unsigned*)(pll + (size_t)s1 * HD);
      unsigned h2 = *(const unsigned*)(phl + (size_t)s2 * HD);
      unsigned l2 = *(const unsigned*)(pll + (size_t)s2 * HD);
      unsigned h3 = *(const unsigned*)(phl + (size_t)s3 * HD);
      unsigned l3 = *(const unsigned*)(pll + (size_t)s3 * HD);
      float2 v0 = recon(h0, l0), v1 = recon(h1, l1);
      float2 v2 = recon(h2, l2), v3 = recon(h3, l3);
      a0.x += v0.x * c0; a0.y += v0.y * c0;
      a1.x += v1.x * c1; a1.y += v1.y * c1;
      a2.x += v2.x * c2; a2.y += v2.y * c2;
      a3.x += v3.x * c3; a3.y += v3.y * c3;
    }
    for (; j < nj; ++j) {
      int s = __builtin_amdgcn_readlane(sreg, j);
      float c = __int_as_float(__builtin_amdgcn_readlane(creg, j));
      float2 v = recon(*(const unsigned*)(phl + (size_t)s * HD),
                       *(const unsigned*)(pll + (size_t)s * HD));
      a0.x += v.x * c; a0.y += v.y * c;
    }
    beg += nj;
  }
  float2 b = *(const float2*)(bias + lane * 2);
  float2 o;
  o.x = tanhf((a0.x + a1.x) + (a2.x + a3.x) + b.x);
  o.y = tanhf((a0.y + a1.y) + (a2.y + a3.y) + b.y);
  if (FINAL) {
    *(float2*)(outf + (size_t)wid * HD + lane * 2) = o;
  } else {
    short h0, l0, h1, l1;
    split2(o.x, h0, l0);
    split2(o.y, h1, l1);
    *(unsigned*)(Ohi + (size_t)wid * HD + lane * 2) =
        (unsigned)(unsigned short)h0 | ((unsigned)(unsigned short)h1 << 16);
    *(unsigned*)(Olo + (size_t)wid * HD + lane * 2) =
        (unsigned)(unsigned short)l0 | ((unsigned)(unsigned short)l1 << 16);
  }
}

extern "C" void kernel_launch(void* const* d_in, const int* in_sizes, int n_in,
                              void* d_out, int out_size, void* d_ws, size_t ws_size,
                              hipStream_t stream) {
  const float* x = (const float*)d_in[0];
  const int* ei = (const int*)d_in[1];   // integer inputs arrive as int32
  const float* W0 = (const float*)d_in[2];
  const float* b0 = (const float*)d_in[3];
  const float* W1 = (const float*)d_in[4];
  const float* b1 = (const float*)d_in[5];
  const float* W2 = (const float*)d_in[6];
  const float* b2 = (const float*)d_in[7];
  const float* W3 = (const float*)d_in[8];
  const float* b3 = (const float*)d_in[9];
  float* out = (float*)d_out;

  char* ws = (char*)d_ws;
  size_t off = 0;
  auto alloc = [&](size_t bytes) -> void* {
    void* p = ws + off;
    off += (bytes + 255) & ~(size_t)255;
    return p;
  };
  int*   cnt      = (int*)alloc((size_t)NN * 4);
  int*   cursor   = (int*)alloc((size_t)NN * 4);
  int*   rowptr   = (int*)alloc((size_t)(NN + 1) * 4);
  int*   partials = (int*)alloc(256 * 4);
  float* dinv     = (float*)alloc((size_t)NN * 4);
  int2*  epack    = (int2*)alloc((size_t)NE * 8);
  short* P1hi     = (short*)alloc((size_t)(NN + 1) * 136 * 2);  // agg-out / x planes
  short* P1lo     = (short*)alloc((size_t)(NN + 1) * 136 * 2);
  short* P2hi     = (short*)alloc((size_t)NN * HD * 2);         // gemm-out planes
  short* P2lo     = (short*)alloc((size_t)NN * HD * 2);
  // total ws ~ 120 MB

  hipMemsetAsync(cnt, 0, (size_t)NN * 4, stream);
  hipMemsetAsync(cursor, 0, (size_t)NN * 4, stream);

  // x -> split planes (KP=136)
  int ptot = (NN + 1) * 136;
  split_x<<<(ptot + 255) / 256, 256, 0, stream>>>(x, P1hi, P1lo, NN);

  // CSR build
  int eb = (NE + 255) / 256;
  cnt_kernel<<<eb, 256, 0, stream>>>(ei, cnt, NE);
  int nb1 = (NN + 1023) / 1024;
  scan1<<<nb1, 256, 0, stream>>>(cnt, rowptr, partials, NN);
  scan2<<<1, 256, 0, stream>>>(partials, nb1);
  scan3<<<(NN + 255) / 256, 256, 0, stream>>>(rowptr, partials, NN, NE);
  dinv_kernel<<<(NN + 255) / 256, 256, 0, stream>>>(cnt, dinv, NN);
  fill_kernel<<<eb, 256, 0, stream>>>(ei, dinv, rowptr, cursor, epack, NE);

  int gb = (NN + 255) / 256;   // 256 rows per block
  int ab = (NN + 3) / 4;       // 1 wave per node

  // layer 0: KP=136, K=133 (KST=5; W rows >=133 zero => tail over-read safe)
  gemm_bf<5><<<gb, 256, 0, stream>>>(P1hi, P1lo, 136, W0, 133, P2hi, P2lo, NN);
  agg_kernel<false><<<ab, 256, 0, stream>>>(P2hi, P2lo, dinv, rowptr, epack, b0,
                                            P1hi, P1lo, nullptr, NN);
  // layers 1-2: KP=128, K=128
  gemm_bf<4><<<gb, 256, 0, stream>>>(P1hi, P1lo, 128, W1, 128, P2hi, P2lo, NN);
  agg_kernel<false><<<ab, 256, 0, stream>>>(P2hi, P2lo, dinv, rowptr, epack, b1,
                                            P1hi, P1lo, nullptr, NN);
  gemm_bf<4><<<gb, 256, 0, stream>>>(P1hi, P1lo, 128, W2, 128, P2hi, P2lo, NN);
  agg_kernel<false><<<ab, 256, 0, stream>>>(P2hi, P2lo, dinv, rowptr, epack, b2,
                                            P1hi, P1lo, nullptr, NN);
  // layer 3: final agg writes f32 d_out
  gemm_bf<4><<<gb, 256, 0, stream>>>(P1hi, P1lo, 128, W3, 128, P2hi, P2lo, NN);
  agg_kernel<true><<<ab, 256, 0, stream>>>(P2hi, P2lo, dinv, rowptr, epack, b3,
                                           nullptr, nullptr, out, NN);
}

// Round 9
// 672.183 us; speedup vs baseline: 1.4482x; 1.4482x over previous
//
#include <hip/hip_runtime.h>
#include <hip/hip_fp16.h>
#include <cmath>

#define NN 100000
#define NE 1600000
#define HD 128

typedef __attribute__((ext_vector_type(8))) short bf16x8;
typedef __attribute__((ext_vector_type(4))) float f32x4;

__device__ inline short f2bf(float f) {
  union { float f; unsigned u; } x; x.f = f;
  unsigned r = x.u + 0x7fff + ((x.u >> 16) & 1);
  return (short)(r >> 16);
}
__device__ inline float bf2f(short s) {
  union { float f; unsigned u; } x;
  x.u = ((unsigned)(unsigned short)s) << 16;
  return x.f;
}
__device__ inline void split2(float v, short& hi, short& lo) {
  hi = f2bf(v);
  lo = f2bf(v - bf2f(hi));
}

// ---------------- prep: split f32 x into bf16 hi/lo planes, KP=136 ----------
__global__ void split_x(const float* __restrict__ x,
                        short* __restrict__ Phi, short* __restrict__ Plo, int n) {
  int i = blockIdx.x * blockDim.x + threadIdx.x;
  int total = (n + 1) * 136;
  if (i >= total) return;
  int row = i / 136;
  int col = i - row * 136;
  float v = (row < n && col < 133) ? x[(size_t)row * 133 + col] : 0.f;
  short hi, lo;
  split2(v, hi, lo);
  Phi[i] = hi;
  Plo[i] = lo;
}

// ---------------- prep: W f32 -> bf16 hi/lo planes in MFMA fragment order ---
template <int KST>
__global__ void wprep(const float* __restrict__ W, int K,
                      short* __restrict__ Fhi, short* __restrict__ Flo) {
  int i = blockIdx.x * blockDim.x + threadIdx.x;
  if (i >= KST * 32 * 128) return;
  int k = i >> 7, col = i & 127;
  float v = (k < K) ? W[k * 128 + col] : 0.f;
  short hi, lo;
  split2(v, hi, lo);
  int off = (((k >> 5) * 8 + (col >> 4)) * 64 + ((k >> 3) & 3) * 16 + (col & 15)) * 8 + (k & 7);
  Fhi[off] = hi;
  Flo[off] = lo;
}

// ---------------- MFMA GEMM: C[n][128] = A[n][K] @ W[K][128] ----------------
// A: pre-split bf16 hi/lo planes (row stride KP). W: fragment-order bf16
// hi/lo planes in GLOBAL memory (L2-broadcast; no LDS, no staging barrier).
// 3-term: Ahi*Whi + Ahi*Wlo + Alo*Whi (~2^-17 rel). Output: fp16 plane
// (consumed only by agg; 11-bit mantissa ~ 1.2e-4 rel).
template <int KST>
__global__ __launch_bounds__(256, 2) void gemm_bf(
    const short* __restrict__ Ahi, const short* __restrict__ Alo, int KP,
    const short* __restrict__ Wfhi, const short* __restrict__ Wflo,
    __half* __restrict__ C, int n) {
  int t = threadIdx.x;
  int wave = t >> 6, lane = t & 63;
  int lrow = lane & 15, khalf = lane >> 4;
  int r0 = blockIdx.x * 256 + wave * 64;

  f32x4 acc[4][8];
#pragma unroll
  for (int rf = 0; rf < 4; ++rf)
#pragma unroll
    for (int cf = 0; cf < 8; ++cf) acc[rf][cf] = (f32x4){0.f, 0.f, 0.f, 0.f};

#pragma unroll
  for (int ks = 0; ks < KST; ++ks) {
    bf16x8 ahi[4], alo[4];
#pragma unroll
    for (int rf = 0; rf < 4; ++rf) {
      int row = r0 + rf * 16 + lrow;
      if (row < n) {
        size_t base = (size_t)row * KP + ks * 32 + khalf * 8;
        ahi[rf] = *(const bf16x8*)(Ahi + base);
        alo[rf] = *(const bf16x8*)(Alo + base);
      } else {
        ahi[rf] = (bf16x8){0, 0, 0, 0, 0, 0, 0, 0};
        alo[rf] = (bf16x8){0, 0, 0, 0, 0, 0, 0, 0};
      }
    }
#pragma unroll
    for (int cf = 0; cf < 8; ++cf) {
      int boff = ((ks * 8 + cf) * 64 + lane) * 8;
      bf16x8 bhi = *(const bf16x8*)(Wfhi + boff);
      bf16x8 blo = *(const bf16x8*)(Wflo + boff);
#pragma unroll
      for (int rf = 0; rf < 4; ++rf) {
        acc[rf][cf] = __builtin_amdgcn_mfma_f32_16x16x32_bf16(ahi[rf], bhi, acc[rf][cf], 0, 0, 0);
        acc[rf][cf] = __builtin_amdgcn_mfma_f32_16x16x32_bf16(ahi[rf], blo, acc[rf][cf], 0, 0, 0);
        acc[rf][cf] = __builtin_amdgcn_mfma_f32_16x16x32_bf16(alo[rf], bhi, acc[rf][cf], 0, 0, 0);
      }
    }
  }

#pragma unroll
  for (int rf = 0; rf < 4; ++rf)
#pragma unroll
    for (int cf = 0; cf < 8; ++cf) {
      int rowb = r0 + rf * 16 + khalf * 4;
      int col = cf * 16 + lrow;
#pragma unroll
      for (int j = 0; j < 4; ++j) {
        int row = rowb + j;
        if (row < n) C[(size_t)row * 128 + col] = __float2half(acc[rf][cf][j]);
      }
    }
}

// ---------------- degree count (int atomics) ----------------
__global__ void cnt_kernel(const int* __restrict__ ei, int* __restrict__ cnt, int e) {
  int i = blockIdx.x * blockDim.x + threadIdx.x;
  if (i < e) atomicAdd(&cnt[ei[(size_t)e + i]], 1);
}

__global__ void dinv_kernel(const int* __restrict__ cnt, float* __restrict__ dinv, int n) {
  int i = blockIdx.x * blockDim.x + threadIdx.x;
  if (i < n) dinv[i] = 1.0f / sqrtf((float)cnt[i] + 1.0f);
}

// ---------------- exclusive scan (3 kernels, 1024 elems/block) ----------------
__global__ __launch_bounds__(256) void scan1(const int* __restrict__ cnt, int* __restrict__ excl,
                                             int* __restrict__ partials, int n) {
  __shared__ int sd[256];
  int t = threadIdx.x;
  int base = blockIdx.x * 1024 + t * 4;
  int v[4]; int s = 0;
#pragma unroll
  for (int i = 0; i < 4; ++i) { int idx = base + i; v[i] = (idx < n) ? cnt[idx] : 0; s += v[i]; }
  sd[t] = s;
  __syncthreads();
  for (int off = 1; off < 256; off <<= 1) {
    int x = (t >= off) ? sd[t - off] : 0;
    __syncthreads();
    if (t >= off) sd[t] += x;
    __syncthreads();
  }
  if (t == 255) partials[blockIdx.x] = sd[255];
  int run = sd[t] - s;
#pragma unroll
  for (int i = 0; i < 4; ++i) { int idx = base + i; if (idx < n) excl[idx] = run; run += v[i]; }
}

__global__ __launch_bounds__(256) void scan2(int* __restrict__ partials, int np) {
  __shared__ int sd[256];
  int t = threadIdx.x;
  int v = (t < np) ? partials[t] : 0;
  sd[t] = v;
  __syncthreads();
  for (int off = 1; off < 256; off <<= 1) {
    int x = (t >= off) ? sd[t - off] : 0;
    __syncthreads();
    if (t >= off) sd[t] += x;
    __syncthreads();
  }
  if (t < np) partials[t] = sd[t] - v;
}

__global__ void scan3(int* __restrict__ rowptr, const int* __restrict__ partials, int n, int etot) {
  int i = blockIdx.x * blockDim.x + threadIdx.x;
  if (i < n) rowptr[i] += partials[i >> 10];
  if (i == 0) rowptr[n] = etot;
}

// ---------------- CSR fill: packed (src, coef) ----------------
__global__ void fill_kernel(const int* __restrict__ ei, const float* __restrict__ dinv,
                            const int* __restrict__ rowptr, int* __restrict__ cursor,
                            int2* __restrict__ epack, int e) {
  int i = blockIdx.x * blockDim.x + threadIdx.x;
  if (i >= e) return;
  int s = ei[i];
  int d = ei[(size_t)e + i];
  int p = atomicAdd(&cursor[d], 1);
  epack[rowptr[d] + p] = make_int2(s, __float_as_int(dinv[s] * dinv[d]));
}

// ---------------- aggregation: gather fp16 h, reg-cached edges --------------
// FINAL=false: writes tanh result as bf16 hi/lo planes (exact next-GEMM path).
// FINAL=true: writes f32 d_out.
template <bool FINAL>
__global__ __launch_bounds__(256) void agg_kernel(
    const __half* __restrict__ H, const float* __restrict__ dinv,
    const int* __restrict__ rowptr, const int2* __restrict__ epack,
    const float* __restrict__ bias,
    short* __restrict__ Ohi, short* __restrict__ Olo,
    float* __restrict__ outf, int n) {
  int wid = (int)((blockIdx.x * (size_t)blockDim.x + threadIdx.x) >> 6);
  int lane = threadIdx.x & 63;
  if (wid >= n) return;
  float di = dinv[wid];
  const __half* hl = H + lane * 2;
  float2 hs = __half22float2(*(const __half2*)(hl + (size_t)wid * HD));
  float2 a0, a1, a2, a3;
  a0.x = hs.x * di * di; a0.y = hs.y * di * di;
  a1.x = a1.y = a2.x = a2.y = a3.x = a3.y = 0.f;
  int beg = rowptr[wid], end = rowptr[wid + 1];
  while (beg < end) {
    int nj = end - beg;
    if (nj > 64) nj = 64;
    int2 ep = (lane < nj) ? epack[beg + lane] : make_int2(0, 0);
    int sreg = ep.x, creg = ep.y;
    int j = 0;
    for (; j + 4 <= nj; j += 4) {
      int s0 = __builtin_amdgcn_readlane(sreg, j + 0);
      int s1 = __builtin_amdgcn_readlane(sreg, j + 1);
      int s2 = __builtin_amdgcn_readlane(sreg, j + 2);
      int s3 = __builtin_amdgcn_readlane(sreg, j + 3);
      float c0 = __int_as_float(__builtin_amdgcn_readlane(creg, j + 0));
      float c1 = __int_as_float(__builtin_amdgcn_readlane(creg, j + 1));
      float c2 = __int_as_float(__builtin_amdgcn_readlane(creg, j + 2));
      float c3 = __int_as_float(__builtin_amdgcn_readlane(creg, j + 3));
      __half2 v0 = *(const __half2*)(hl + (size_t)s0 * HD);
      __half2 v1 = *(const __half2*)(hl + (size_t)s1 * HD);
      __half2 v2 = *(const __half2*)(hl + (size_t)s2 * HD);
      __half2 v3 = *(const __half2*)(hl + (size_t)s3 * HD);
      float2 f0 = __half22float2(v0), f1 = __half22float2(v1);
      float2 f2 = __half22float2(v2), f3 = __half22float2(v3);
      a0.x += f0.x * c0; a0.y += f0.y * c0;
      a1.x += f1.x * c1; a1.y += f1.y * c1;
      a2.x += f2.x * c2; a2.y += f2.y * c2;
      a3.x += f3.x * c3; a3.y += f3.y * c3;
    }
    for (; j < nj; ++j) {
      int s = __builtin_amdgcn_readlane(sreg, j);
      float c = __int_as_float(__builtin_amdgcn_readlane(creg, j));
      float2 v = __half22float2(*(const __half2*)(hl + (size_t)s * HD));
      a0.x += v.x * c; a0.y += v.y * c;
    }
    beg += nj;
  }
  float2 b = *(const float2*)(bias + lane * 2);
  float2 o;
  o.x = tanhf((a0.x + a1.x) + (a2.x + a3.x) + b.x);
  o.y = tanhf((a0.y + a1.y) + (a2.y + a3.y) + b.y);
  if (FINAL) {
    *(float2*)(outf + (size_t)wid * HD + lane * 2) = o;
  } else {
    short h0, l0, h1, l1;
    split2(o.x, h0, l0);
    split2(o.y, h1, l1);
    *(unsigned*)(Ohi + (size_t)wid * HD + lane * 2) =
        (unsigned)(unsigned short)h0 | ((unsigned)(unsigned short)h1 << 16);
    *(unsigned*)(Olo + (size_t)wid * HD + lane * 2) =
        (unsigned)(unsigned short)l0 | ((unsigned)(unsigned short)l1 << 16);
  }
}

extern "C" void kernel_launch(void* const* d_in, const int* in_sizes, int n_in,
                              void* d_out, int out_size, void* d_ws, size_t ws_size,
                              hipStream_t stream) {
  const float* x = (const float*)d_in[0];
  const int* ei = (const int*)d_in[1];   // integer inputs arrive as int32
  const float* W0 = (const float*)d_in[2];
  const float* b0 = (const float*)d_in[3];
  const float* W1 = (const float*)d_in[4];
  const float* b1 = (const float*)d_in[5];
  const float* W2 = (const float*)d_in[6];
  const float* b2 = (const float*)d_in[7];
  const float* W3 = (const float*)d_in[8];
  const float* b3 = (const float*)d_in[9];
  float* out = (float*)d_out;

  char* ws = (char*)d_ws;
  size_t off = 0;
  auto alloc = [&](size_t bytes) -> void* {
    void* p = ws + off;
    off += (bytes + 255) & ~(size_t)255;
    return p;
  };
  int*   cnt      = (int*)alloc((size_t)NN * 4);
  int*   cursor   = (int*)alloc((size_t)NN * 4);
  int*   rowptr   = (int*)alloc((size_t)(NN + 1) * 4);
  int*   partials = (int*)alloc(256 * 4);
  float* dinv     = (float*)alloc((size_t)NN * 4);
  int2*  epack    = (int2*)alloc((size_t)NE * 8);
  short* P1hi     = (short*)alloc((size_t)(NN + 1) * 136 * 2);  // gemm-input planes
  short* P1lo     = (short*)alloc((size_t)(NN + 1) * 136 * 2);
  __half* Hf      = (__half*)alloc((size_t)NN * HD * 2);        // gemm-output fp16
  short* w0hi     = (short*)alloc(5 * 32 * 128 * 2);            // W frag planes
  short* w0lo     = (short*)alloc(5 * 32 * 128 * 2);
  short* w1hi     = (short*)alloc(4 * 32 * 128 * 2);
  short* w1lo     = (short*)alloc(4 * 32 * 128 * 2);
  short* w2hi     = (short*)alloc(4 * 32 * 128 * 2);
  short* w2lo     = (short*)alloc(4 * 32 * 128 * 2);
  short* w3hi     = (short*)alloc(4 * 32 * 128 * 2);
  short* w3lo     = (short*)alloc(4 * 32 * 128 * 2);
  // total ws ~ 95 MB

  hipMemsetAsync(cnt, 0, (size_t)NN * 4, stream);
  hipMemsetAsync(cursor, 0, (size_t)NN * 4, stream);

  // prep: x planes + W fragment planes
  int ptot = (NN + 1) * 136;
  split_x<<<(ptot + 255) / 256, 256, 0, stream>>>(x, P1hi, P1lo, NN);
  wprep<5><<<(5 * 32 * 128 + 255) / 256, 256, 0, stream>>>(W0, 133, w0hi, w0lo);
  wprep<4><<<(4 * 32 * 128 + 255) / 256, 256, 0, stream>>>(W1, 128, w1hi, w1lo);
  wprep<4><<<(4 * 32 * 128 + 255) / 256, 256, 0, stream>>>(W2, 128, w2hi, w2lo);
  wprep<4><<<(4 * 32 * 128 + 255) / 256, 256, 0, stream>>>(W3, 128, w3hi, w3lo);

  // CSR build
  int eb = (NE + 255) / 256;
  cnt_kernel<<<eb, 256, 0, stream>>>(ei, cnt, NE);
  int nb1 = (NN + 1023) / 1024;
  scan1<<<nb1, 256, 0, stream>>>(cnt, rowptr, partials, NN);
  scan2<<<1, 256, 0, stream>>>(partials, nb1);
  scan3<<<(NN + 255) / 256, 256, 0, stream>>>(rowptr, partials, NN, NE);
  dinv_kernel<<<(NN + 255) / 256, 256, 0, stream>>>(cnt, dinv, NN);
  fill_kernel<<<eb, 256, 0, stream>>>(ei, dinv, rowptr, cursor, epack, NE);

  int gb = (NN + 255) / 256;   // 256 rows per block
  int ab = (NN + 3) / 4;       // 1 wave per node

  // layer 0: KP=136, K=133 (KST=5; W rows >=133 zero => tail over-read safe)
  gemm_bf<5><<<gb, 256, 0, stream>>>(P1hi, P1lo, 136, w0hi, w0lo, Hf, NN);
  agg_kernel<false><<<ab, 256, 0, stream>>>(Hf, dinv, rowptr, epack, b0,
                                            P1hi, P1lo, nullptr, NN);
  // layers 1-2: KP=128
  gemm_bf<4><<<gb, 256, 0, stream>>>(P1hi, P1lo, 128, w1hi, w1lo, Hf, NN);
  agg_kernel<false><<<ab, 256, 0, stream>>>(Hf, dinv, rowptr, epack, b1,
                                            P1hi, P1lo, nullptr, NN);
  gemm_bf<4><<<gb, 256, 0, stream>>>(P1hi, P1lo, 128, w2hi, w2lo, Hf, NN);
  agg_kernel<false><<<ab, 256, 0, stream>>>(Hf, dinv, rowptr, epack, b2,
                                            P1hi, P1lo, nullptr, NN);
  // layer 3: final agg writes f32 d_out
  gemm_bf<4><<<gb, 256, 0, stream>>>(P1hi, P1lo, 128, w3hi, w3lo, Hf, NN);
  agg_kernel<true><<<ab, 256, 0, stream>>>(Hf, dinv, rowptr, epack, b3,
                                           nullptr, nullptr, out, NN);
}